// Round 4
// baseline (104.306 us; speedup 1.0000x reference)
//
#include <hip/hip_runtime.h>
#include <hip/hip_bf16.h>

#define N_NODES 100000
#define N_EDGES 1600000
#define IN_F 256
#define OUT_F 64

typedef short bf16x8 __attribute__((ext_vector_type(8)));
typedef float f32x4 __attribute__((ext_vector_type(4)));
typedef unsigned short u16x4 __attribute__((ext_vector_type(4)));

__device__ __forceinline__ short f2bf(float f) {
  unsigned u = __float_as_uint(f);
  u += 0x7FFF + ((u >> 16) & 1);  // round-to-nearest-even
  return (short)(u >> 16);
}
__device__ __forceinline__ float bf2f(unsigned short u) {
  return __uint_as_float(((unsigned)u) << 16);
}

// ---------------------------------------------------------------------------
// Kernel 1: CSR row pointers from sorted row_idx (binary search).
// ---------------------------------------------------------------------------
__global__ __launch_bounds__(256) void build_row_ptr_kernel(
    const int* __restrict__ row_idx, int* __restrict__ row_ptr) {
  int i = blockIdx.x * blockDim.x + threadIdx.x;
  if (i > N_NODES) return;
  int lo = 0, hi = N_EDGES;
  while (lo < hi) {
    int mid = (lo + hi) >> 1;
    if (row_idx[mid] < i) lo = mid + 1; else hi = mid;
  }
  row_ptr[i] = lo;
}

// ---------------------------------------------------------------------------
// Kernel 1b: precompute W as bf16 MFMA B-fragments, fragment-major.
//   k = s*32 + (l>>4)*8 + j, col = t*16 + (l&15)
// ---------------------------------------------------------------------------
__global__ __launch_bounds__(256) void wfrag_kernel(
    const float* __restrict__ W, short* __restrict__ Wf) {
  int tid = blockIdx.x * blockDim.x + threadIdx.x;  // [0, 2048)
  if (tid >= 2048) return;
  int s = tid >> 8;
  int r = tid & 255;
  int t = r >> 6;
  int lane = r & 63;
  int col = t * 16 + (lane & 15);
  int kbase = s * 32 + ((lane >> 4) & 3) * 8;
#pragma unroll
  for (int j = 0; j < 8; ++j) {
    Wf[(size_t)tid * 8 + j] = f2bf(W[(size_t)(kbase + j) * OUT_F + col]);
  }
}

// ---------------------------------------------------------------------------
// Kernel 2: support(bf16) = x @ W via bf16 MFMA (16x16x32).
// x loads are nontemporal (pure 102MB stream, read-once) so they don't evict
// freshly written supB lines from L2 before the spmm starts.
// C/D layout (HW-verified): col = lane&15, row = (lane>>4)*4 + reg.
// ---------------------------------------------------------------------------
__global__ __launch_bounds__(256) void gemm_kernel(
    const float* __restrict__ x, const short* __restrict__ Wf,
    unsigned short* __restrict__ supB) {
  __shared__ short sWf[8 * 4 * 64 * 8];  // 32 KB
  {
    const float4* g = reinterpret_cast<const float4*>(Wf);
    float4* s4 = reinterpret_cast<float4*>(sWf);
#pragma unroll
    for (int i = 0; i < 8; ++i) s4[threadIdx.x + i * 256] = g[threadIdx.x + i * 256];
  }
  __syncthreads();

  const int lane = threadIdx.x & 63;
  const int wave = threadIdx.x >> 6;
  const int r0_base = blockIdx.x * 64 + wave * 16;

  int arow = r0_base + (lane & 15);
  if (arow >= N_NODES) arow = N_NODES - 1;
  const float* xrow = x + (size_t)arow * IN_F + ((lane >> 4) & 3) * 8;

  f32x4 acc0 = {0.f, 0.f, 0.f, 0.f};
  f32x4 acc1 = {0.f, 0.f, 0.f, 0.f};
  f32x4 acc2 = {0.f, 0.f, 0.f, 0.f};
  f32x4 acc3 = {0.f, 0.f, 0.f, 0.f};

#pragma unroll
  for (int s = 0; s < 8; ++s) {
    const f32x4 f0 = __builtin_nontemporal_load(
        reinterpret_cast<const f32x4*>(xrow + s * 32));
    const f32x4 f1 = __builtin_nontemporal_load(
        reinterpret_cast<const f32x4*>(xrow + s * 32 + 4));
    bf16x8 a;
    a[0] = f2bf(f0[0]); a[1] = f2bf(f0[1]); a[2] = f2bf(f0[2]); a[3] = f2bf(f0[3]);
    a[4] = f2bf(f1[0]); a[5] = f2bf(f1[1]); a[6] = f2bf(f1[2]); a[7] = f2bf(f1[3]);
    const bf16x8 b0 = *reinterpret_cast<const bf16x8*>(&sWf[((s * 4 + 0) * 64 + lane) * 8]);
    const bf16x8 b1 = *reinterpret_cast<const bf16x8*>(&sWf[((s * 4 + 1) * 64 + lane) * 8]);
    const bf16x8 b2 = *reinterpret_cast<const bf16x8*>(&sWf[((s * 4 + 2) * 64 + lane) * 8]);
    const bf16x8 b3 = *reinterpret_cast<const bf16x8*>(&sWf[((s * 4 + 3) * 64 + lane) * 8]);
    acc0 = __builtin_amdgcn_mfma_f32_16x16x32_bf16(a, b0, acc0, 0, 0, 0);
    acc1 = __builtin_amdgcn_mfma_f32_16x16x32_bf16(a, b1, acc1, 0, 0, 0);
    acc2 = __builtin_amdgcn_mfma_f32_16x16x32_bf16(a, b2, acc2, 0, 0, 0);
    acc3 = __builtin_amdgcn_mfma_f32_16x16x32_bf16(a, b3, acc3, 0, 0, 0);
  }

  const int orow_base = r0_base + ((lane >> 4) & 3) * 4;
  const int ocol = lane & 15;
#pragma unroll
  for (int r = 0; r < 4; ++r) {
    const int row = orow_base + r;
    if (row < N_NODES) {
      unsigned short* o = supB + (size_t)row * OUT_F + ocol;
      o[0]  = (unsigned short)f2bf(acc0[r]);
      o[16] = (unsigned short)f2bf(acc1[r]);
      o[32] = (unsigned short)f2bf(acc2[r]);
      o[48] = (unsigned short)f2bf(acc3[r]);
    }
  }
}

// ---------------------------------------------------------------------------
// Kernel 3: out[n] = bias + sum_{e in row n} ev[e] * supB[col[e]]
// Contiguous node range per wave (col/ev become per-wave sequential streams).
// Two nodes processed in one interleaved loop, 2 batches of 4 edges each ->
// 16 edges (4 gathers/lane) in flight per latency window. Uniform branches
// only. col/ev loads and out stores nontemporal (single-use streams) to
// preserve L2 for the supB gather. Deterministic, no atomics.
// ---------------------------------------------------------------------------
__global__ __launch_bounds__(256) void spmm_kernel(
    const unsigned short* __restrict__ supB, const float* __restrict__ ev,
    const int* __restrict__ col, const int* __restrict__ row_ptr,
    const float* __restrict__ bias, float* __restrict__ out) {
  const int lane = threadIdx.x & 63;
  const int g = lane >> 4;
  const int fq = lane & 15;
  const int gwave = (blockIdx.x * blockDim.x + threadIdx.x) >> 6;
  const int nwaves = (gridDim.x * blockDim.x) >> 6;

  const int per = (N_NODES + nwaves - 1) / nwaves;
  const int n0 = gwave * per;
  if (n0 >= N_NODES) return;
  const int n1 = (n0 + per < N_NODES) ? n0 + per : N_NODES;

  const float b0 = bias[fq * 4 + 0];
  const float b1 = bias[fq * 4 + 1];
  const float b2 = bias[fq * 4 + 2];
  const float b3 = bias[fq * 4 + 3];

  int sA = row_ptr[n0];
  for (int nn = n0; nn < n1; nn += 2) {
    const bool hasB = (nn + 1 < n1);
    const int m  = row_ptr[nn + 1];
    const int eB = hasB ? row_ptr[nn + 2] : m;

    float aA0 = 0.f, aA1 = 0.f, aA2 = 0.f, aA3 = 0.f;
    float aB0 = 0.f, aB1 = 0.f, aB2 = 0.f, aB3 = 0.f;

    int iA = sA, iB = m;
    while (iA < m || iB < eB) {
      const int a0i = iA + g,     a1i = iA + 4 + g;
      const int b0i = iB + g,     b1i = iB + 4 + g;
      const bool pa0 = a0i < m,   pa1 = a1i < m;
      const bool pb0 = b0i < eB,  pb1 = b1i < eB;

      const int   ca0 = pa0 ? __builtin_nontemporal_load(col + a0i) : 0;
      const int   ca1 = pa1 ? __builtin_nontemporal_load(col + a1i) : 0;
      const int   cb0 = pb0 ? __builtin_nontemporal_load(col + b0i) : 0;
      const int   cb1 = pb1 ? __builtin_nontemporal_load(col + b1i) : 0;
      const float va0 = pa0 ? __builtin_nontemporal_load(ev + a0i) : 0.f;
      const float va1 = pa1 ? __builtin_nontemporal_load(ev + a1i) : 0.f;
      const float vb0 = pb0 ? __builtin_nontemporal_load(ev + b0i) : 0.f;
      const float vb1 = pb1 ? __builtin_nontemporal_load(ev + b1i) : 0.f;

      const u16x4 sa0 = *reinterpret_cast<const u16x4*>(supB + (size_t)ca0 * OUT_F + fq * 4);
      const u16x4 sa1 = *reinterpret_cast<const u16x4*>(supB + (size_t)ca1 * OUT_F + fq * 4);
      const u16x4 sb0 = *reinterpret_cast<const u16x4*>(supB + (size_t)cb0 * OUT_F + fq * 4);
      const u16x4 sb1 = *reinterpret_cast<const u16x4*>(supB + (size_t)cb1 * OUT_F + fq * 4);

      aA0 = fmaf(va0, bf2f(sa0[0]), aA0); aA0 = fmaf(va1, bf2f(sa1[0]), aA0);
      aA1 = fmaf(va0, bf2f(sa0[1]), aA1); aA1 = fmaf(va1, bf2f(sa1[1]), aA1);
      aA2 = fmaf(va0, bf2f(sa0[2]), aA2); aA2 = fmaf(va1, bf2f(sa1[2]), aA2);
      aA3 = fmaf(va0, bf2f(sa0[3]), aA3); aA3 = fmaf(va1, bf2f(sa1[3]), aA3);
      aB0 = fmaf(vb0, bf2f(sb0[0]), aB0); aB0 = fmaf(vb1, bf2f(sb1[0]), aB0);
      aB1 = fmaf(vb0, bf2f(sb0[1]), aB1); aB1 = fmaf(vb1, bf2f(sb1[1]), aB1);
      aB2 = fmaf(vb0, bf2f(sb0[2]), aB2); aB2 = fmaf(vb1, bf2f(sb1[2]), aB2);
      aB3 = fmaf(vb0, bf2f(sb0[3]), aB3); aB3 = fmaf(vb1, bf2f(sb1[3]), aB3);

      iA += 8; iB += 8;
    }

    aA0 += __shfl_xor(aA0, 16); aA0 += __shfl_xor(aA0, 32);
    aA1 += __shfl_xor(aA1, 16); aA1 += __shfl_xor(aA1, 32);
    aA2 += __shfl_xor(aA2, 16); aA2 += __shfl_xor(aA2, 32);
    aA3 += __shfl_xor(aA3, 16); aA3 += __shfl_xor(aA3, 32);
    aB0 += __shfl_xor(aB0, 16); aB0 += __shfl_xor(aB0, 32);
    aB1 += __shfl_xor(aB1, 16); aB1 += __shfl_xor(aB1, 32);
    aB2 += __shfl_xor(aB2, 16); aB2 += __shfl_xor(aB2, 32);
    aB3 += __shfl_xor(aB3, 16); aB3 += __shfl_xor(aB3, 32);

    if (lane < 16) {
      f32x4 oA = {aA0 + b0, aA1 + b1, aA2 + b2, aA3 + b3};
      __builtin_nontemporal_store(
          oA, reinterpret_cast<f32x4*>(out + (size_t)nn * OUT_F + fq * 4));
      if (hasB) {
        f32x4 oB = {aB0 + b0, aB1 + b1, aB2 + b2, aB3 + b3};
        __builtin_nontemporal_store(
            oB, reinterpret_cast<f32x4*>(out + (size_t)(nn + 1) * OUT_F + fq * 4));
      }
    }
    sA = eB;
  }
}

extern "C" void kernel_launch(void* const* d_in, const int* in_sizes, int n_in,
                              void* d_out, int out_size, void* d_ws, size_t ws_size,
                              hipStream_t stream) {
  const float* x        = (const float*)d_in[0];
  const float* ev       = (const float*)d_in[1];
  const float* W        = (const float*)d_in[2];
  const float* bias     = (const float*)d_in[3];
  const int*   row_idx  = (const int*)d_in[4];
  const int*   col_idx  = (const int*)d_in[5];
  float* out = (float*)d_out;

  // Workspace: [0, 400KB) row_ptr; [448KB, 480KB) W-fragments (bf16);
  //            [512KB, +12.8MB) support bf16.
  int*            row_ptr = (int*)d_ws;
  short*          Wf      = (short*)((char*)d_ws + 448 * 1024);
  unsigned short* supB    = (unsigned short*)((char*)d_ws + 512 * 1024);

  build_row_ptr_kernel<<<(N_NODES + 1 + 255) / 256, 256, 0, stream>>>(row_idx, row_ptr);
  wfrag_kernel<<<8, 256, 0, stream>>>(W, Wf);

  gemm_kernel<<<(N_NODES + 63) / 64, 256, 0, stream>>>(x, Wf, supB);

  spmm_kernel<<<2048, 256, 0, stream>>>(supB, ev, col_idx, row_ptr, bias, out);
}

// Round 5
// 71.393 us; speedup vs baseline: 1.4610x; 1.4610x over previous
//
#include <hip/hip_runtime.h>
#include <hip/hip_bf16.h>

#define N_NODES 100000
#define N_EDGES 1600000
#define IN_F 256
#define OUT_F 64

typedef short bf16x8 __attribute__((ext_vector_type(8)));
typedef float f32x4 __attribute__((ext_vector_type(4)));
typedef unsigned short u16x8 __attribute__((ext_vector_type(8)));

__device__ __forceinline__ short f2bf(float f) {
  unsigned u = __float_as_uint(f);
  u += 0x7FFF + ((u >> 16) & 1);  // round-to-nearest-even
  return (short)(u >> 16);
}
__device__ __forceinline__ float bf2f(unsigned short u) {
  return __uint_as_float(((unsigned)u) << 16);
}

// ---------------------------------------------------------------------------
// Kernel 1: CSR row pointers from sorted row_idx (binary search).
// ---------------------------------------------------------------------------
__global__ __launch_bounds__(256) void build_row_ptr_kernel(
    const int* __restrict__ row_idx, int* __restrict__ row_ptr) {
  int i = blockIdx.x * blockDim.x + threadIdx.x;
  if (i > N_NODES) return;
  int lo = 0, hi = N_EDGES;
  while (lo < hi) {
    int mid = (lo + hi) >> 1;
    if (row_idx[mid] < i) lo = mid + 1; else hi = mid;
  }
  row_ptr[i] = lo;
}

// ---------------------------------------------------------------------------
// Kernel 1b: precompute W as bf16 MFMA B-fragments, fragment-major.
//   k = s*32 + (l>>4)*8 + j, col = t*16 + (l&15)
// ---------------------------------------------------------------------------
__global__ __launch_bounds__(256) void wfrag_kernel(
    const float* __restrict__ W, short* __restrict__ Wf) {
  int tid = blockIdx.x * blockDim.x + threadIdx.x;  // [0, 2048)
  if (tid >= 2048) return;
  int s = tid >> 8;
  int r = tid & 255;
  int t = r >> 6;
  int lane = r & 63;
  int col = t * 16 + (lane & 15);
  int kbase = s * 32 + ((lane >> 4) & 3) * 8;
#pragma unroll
  for (int j = 0; j < 8; ++j) {
    Wf[(size_t)tid * 8 + j] = f2bf(W[(size_t)(kbase + j) * OUT_F + col]);
  }
}

// ---------------------------------------------------------------------------
// Kernel 2: support(bf16) = x @ W via bf16 MFMA (16x16x32).
// Plain (cached) loads — NT experiment reverted, it regressed.
// C/D layout (HW-verified): col = lane&15, row = (lane>>4)*4 + reg.
// ---------------------------------------------------------------------------
__global__ __launch_bounds__(256) void gemm_kernel(
    const float* __restrict__ x, const short* __restrict__ Wf,
    unsigned short* __restrict__ supB) {
  __shared__ short sWf[8 * 4 * 64 * 8];  // 32 KB
  {
    const float4* g = reinterpret_cast<const float4*>(Wf);
    float4* s4 = reinterpret_cast<float4*>(sWf);
#pragma unroll
    for (int i = 0; i < 8; ++i) s4[threadIdx.x + i * 256] = g[threadIdx.x + i * 256];
  }
  __syncthreads();

  const int lane = threadIdx.x & 63;
  const int wave = threadIdx.x >> 6;
  const int r0_base = blockIdx.x * 64 + wave * 16;

  int arow = r0_base + (lane & 15);
  if (arow >= N_NODES) arow = N_NODES - 1;
  const float* xrow = x + (size_t)arow * IN_F + ((lane >> 4) & 3) * 8;

  f32x4 acc0 = {0.f, 0.f, 0.f, 0.f};
  f32x4 acc1 = {0.f, 0.f, 0.f, 0.f};
  f32x4 acc2 = {0.f, 0.f, 0.f, 0.f};
  f32x4 acc3 = {0.f, 0.f, 0.f, 0.f};

#pragma unroll
  for (int s = 0; s < 8; ++s) {
    const float4 f0 = *reinterpret_cast<const float4*>(xrow + s * 32);
    const float4 f1 = *reinterpret_cast<const float4*>(xrow + s * 32 + 4);
    bf16x8 a;
    a[0] = f2bf(f0.x); a[1] = f2bf(f0.y); a[2] = f2bf(f0.z); a[3] = f2bf(f0.w);
    a[4] = f2bf(f1.x); a[5] = f2bf(f1.y); a[6] = f2bf(f1.z); a[7] = f2bf(f1.w);
    const bf16x8 b0 = *reinterpret_cast<const bf16x8*>(&sWf[((s * 4 + 0) * 64 + lane) * 8]);
    const bf16x8 b1 = *reinterpret_cast<const bf16x8*>(&sWf[((s * 4 + 1) * 64 + lane) * 8]);
    const bf16x8 b2 = *reinterpret_cast<const bf16x8*>(&sWf[((s * 4 + 2) * 64 + lane) * 8]);
    const bf16x8 b3 = *reinterpret_cast<const bf16x8*>(&sWf[((s * 4 + 3) * 64 + lane) * 8]);
    acc0 = __builtin_amdgcn_mfma_f32_16x16x32_bf16(a, b0, acc0, 0, 0, 0);
    acc1 = __builtin_amdgcn_mfma_f32_16x16x32_bf16(a, b1, acc1, 0, 0, 0);
    acc2 = __builtin_amdgcn_mfma_f32_16x16x32_bf16(a, b2, acc2, 0, 0, 0);
    acc3 = __builtin_amdgcn_mfma_f32_16x16x32_bf16(a, b3, acc3, 0, 0, 0);
  }

  const int orow_base = r0_base + ((lane >> 4) & 3) * 4;
  const int ocol = lane & 15;
#pragma unroll
  for (int r = 0; r < 4; ++r) {
    const int row = orow_base + r;
    if (row < N_NODES) {
      unsigned short* o = supB + (size_t)row * OUT_F + ocol;
      o[0]  = (unsigned short)f2bf(acc0[r]);
      o[16] = (unsigned short)f2bf(acc1[r]);
      o[32] = (unsigned short)f2bf(acc2[r]);
      o[48] = (unsigned short)f2bf(acc3[r]);
    }
  }
}

// ---------------------------------------------------------------------------
// Kernel 3: out[n] = bias + sum_{e in row n} ev[e] * supB[col[e]]
// Strided node assignment (reverted). lane -> (g = lane>>3: edge subgroup
// 0..7, fo = lane&7: feature octet). Each lane loads 16 B (8 bf16) of edge
// i+g and i+8+g -> one instr covers 8 edges, 16 edges in flight per window.
// Typical node (deg~16) = ONE latency window. Reduce = 3 shfl_xor per acc;
// lanes 0-7 store 32 B each. Deterministic, no atomics.
// ---------------------------------------------------------------------------
__global__ __launch_bounds__(256) void spmm_kernel(
    const unsigned short* __restrict__ supB, const float* __restrict__ ev,
    const int* __restrict__ col, const int* __restrict__ row_ptr,
    const float* __restrict__ bias, float* __restrict__ out) {
  const int lane = threadIdx.x & 63;
  const int g = lane >> 3;   // edge subgroup 0..7
  const int fo = lane & 7;   // feature octet 0..7
  const int gwave = (blockIdx.x * blockDim.x + threadIdx.x) >> 6;
  const int nwaves = (gridDim.x * blockDim.x) >> 6;

  float b[8];
#pragma unroll
  for (int j = 0; j < 8; ++j) b[j] = bias[fo * 8 + j];

  for (int node = gwave; node < N_NODES; node += nwaves) {
    const int s = row_ptr[node];
    const int e = row_ptr[node + 1];
    float acc[8] = {0.f, 0.f, 0.f, 0.f, 0.f, 0.f, 0.f, 0.f};

    for (int i = s; i < e; i += 16) {
      const int i0 = i + g;
      const int i1 = i + 8 + g;
      const bool p0 = i0 < e;
      const bool p1 = i1 < e;
      const int c0 = col[p0 ? i0 : s];   // clamped: valid & warm line
      const int c1 = col[p1 ? i1 : s];
      const float v0 = p0 ? ev[i0] : 0.f;
      const float v1 = p1 ? ev[i1] : 0.f;
      const u16x8 s0 = *reinterpret_cast<const u16x8*>(supB + (size_t)c0 * OUT_F + fo * 8);
      const u16x8 s1 = *reinterpret_cast<const u16x8*>(supB + (size_t)c1 * OUT_F + fo * 8);
#pragma unroll
      for (int j = 0; j < 8; ++j) acc[j] = fmaf(v0, bf2f(s0[j]), acc[j]);
#pragma unroll
      for (int j = 0; j < 8; ++j) acc[j] = fmaf(v1, bf2f(s1[j]), acc[j]);
    }

    // reduce across the 8 edge subgroups (lane bits 3,4,5)
#pragma unroll
    for (int j = 0; j < 8; ++j) {
      acc[j] += __shfl_xor(acc[j], 8);
      acc[j] += __shfl_xor(acc[j], 16);
      acc[j] += __shfl_xor(acc[j], 32);
    }

    if (lane < 8) {
      f32x4 oA = {acc[0] + b[0], acc[1] + b[1], acc[2] + b[2], acc[3] + b[3]};
      f32x4 oB = {acc[4] + b[4], acc[5] + b[5], acc[6] + b[6], acc[7] + b[7]};
      float* o = out + (size_t)node * OUT_F + fo * 8;
      *reinterpret_cast<f32x4*>(o) = oA;
      *reinterpret_cast<f32x4*>(o + 4) = oB;
    }
  }
}

extern "C" void kernel_launch(void* const* d_in, const int* in_sizes, int n_in,
                              void* d_out, int out_size, void* d_ws, size_t ws_size,
                              hipStream_t stream) {
  const float* x        = (const float*)d_in[0];
  const float* ev       = (const float*)d_in[1];
  const float* W        = (const float*)d_in[2];
  const float* bias     = (const float*)d_in[3];
  const int*   row_idx  = (const int*)d_in[4];
  const int*   col_idx  = (const int*)d_in[5];
  float* out = (float*)d_out;

  // Workspace: [0, 400KB) row_ptr; [448KB, 480KB) W-fragments (bf16);
  //            [512KB, +12.8MB) support bf16.
  int*            row_ptr = (int*)d_ws;
  short*          Wf      = (short*)((char*)d_ws + 448 * 1024);
  unsigned short* supB    = (unsigned short*)((char*)d_ws + 512 * 1024);

  build_row_ptr_kernel<<<(N_NODES + 1 + 255) / 256, 256, 0, stream>>>(row_idx, row_ptr);
  wfrag_kernel<<<8, 256, 0, stream>>>(W, Wf);

  gemm_kernel<<<(N_NODES + 63) / 64, 256, 0, stream>>>(x, Wf, supB);

  spmm_kernel<<<2048, 256, 0, stream>>>(supB, ev, col_idx, row_ptr, bias, out);
}